// Round 4
// baseline (1179.245 us; speedup 1.0000x reference)
//
#include <hip/hip_runtime.h>
#include <cstdint>
#include <math.h>

#define MASK_VAL (-1e30f)

#define Bb   64
#define VN   100
#define QN   64
#define KN   64
#define VD   2048
#define QD   768
#define KGD  300
#define KGP  320            /* KGD padded to mult of 32 */
#define HH   1024
#define RR   32
#define HDm  32
#define GG   2
#define NBV  (Bb*VN)              /* 6400 */
#define LOGN ((size_t)NBV*QN*KN*GG) /* 52,428,800 */

typedef _Float16 half_t;
typedef _Float16 f16x8 __attribute__((ext_vector_type(8)));
typedef float    f32x4 __attribute__((ext_vector_type(4)));

#define MFMA_F16(a,b,c) __builtin_amdgcn_mfma_f32_16x16x32_f16(a,b,c,0,0,0)

// ---------------- cast2d: dst[r][c] = (r<Rs && c<Cs) ? (half)src[r*Cs+c] : 0 ----------------
__global__ __launch_bounds__(256) void cast2d_kernel(const float* __restrict__ src,
                                                     half_t* __restrict__ dst,
                                                     int Rd, int Cd, int Rs, int Cs)
{
  int idx = blockIdx.x*256 + threadIdx.x;
  int total = Rd*Cd;
  if (idx >= total) return;
  int r = idx / Cd, c = idx - r*Cd;
  float v = (r < Rs && c < Cs) ? src[(size_t)r*Cs + c] : 0.f;
  dst[idx] = (half_t)v;
}

// ---------------- castT: dst[n][k] = (k<Ks) ? (half)src[k][n] : 0 ; n in [0,1024) ----------
__global__ __launch_bounds__(256) void castT_kernel(const float* __restrict__ src,
                                                    half_t* __restrict__ dst,
                                                    int Kd, int Ks)
{
  int idx = blockIdx.x*256 + threadIdx.x;
  int total = HH*Kd;
  if (idx >= total) return;
  int n = idx / Kd, k = idx - n*Kd;
  dst[idx] = (half_t)((k < Ks) ? src[(size_t)k*HH + n] : 0.f);
}

// ---------------- permT: Tpp[r][ (zg*32+y)*32 + x ] = (half) T[(r*32+x)*2048 + y*64 + zg] ----
__global__ __launch_bounds__(256) void permT_kernel(const float* __restrict__ Tg,
                                                    half_t* __restrict__ Tpp)
{
  int idx = blockIdx.x*256 + threadIdx.x;
  if (idx >= 32*65536) return;
  int r = idx >> 16, rem = idx & 65535;
  int cp = rem >> 5, x = rem & 31;
  int y = cp & 31, zg = cp >> 5;
  Tpp[idx] = (half_t)Tg[((size_t)(r*32 + x) << 11) + y*64 + zg];
}

// ---------------- mask ----------------
__global__ __launch_bounds__(256) void mask_kernel(const float* __restrict__ v,
                                                   float* __restrict__ maskv)
{
  int row = blockIdx.x;
  int tid = threadIdx.x;
  const float* src = v + (size_t)row * VD;
  float s = 0.f;
  for (int i = tid; i < VD/4; i += 256) {
    float4 x = *(const float4*)&src[i*4];
    s += fabsf(x.x)+fabsf(x.y)+fabsf(x.z)+fabsf(x.w);
  }
#pragma unroll
  for (int off=32; off; off>>=1) s += __shfl_down(s, off);
  __shared__ float red[4];
  if ((tid & 63) == 0) red[tid>>6] = s;
  __syncthreads();
  if (tid == 0) maskv[row] = ((red[0]+red[1]+red[2]+red[3]) == 0.f) ? 1.f : 0.f;
}

// ---------------- proj (MFMA): H[M][1024] = relu(A[M][Kp] @ W + b), A fp16, Wt[n][k] fp16 ----
__global__ __launch_bounds__(256) void proj_mfma_kernel(const half_t* __restrict__ A,
                                                        const half_t* __restrict__ Wt,
                                                        const float* __restrict__ bias,
                                                        half_t* __restrict__ H, int Kp)
{
  int w = threadIdx.x >> 6, lane = threadIdx.x & 63;
  int m0 = blockIdx.x*64 + w*16;
  int n0 = blockIdx.y*64;
  int lr = lane & 15, lc = lane >> 4;
  f32x4 acc[4];
#pragma unroll
  for (int nt=0;nt<4;nt++) acc[nt] = (f32x4)(0.f);
  const half_t* arow = A + (size_t)(m0 + lr)*Kp + lc*8;
  for (int k0 = 0; k0 < Kp; k0 += 32) {
    f16x8 a = *(const f16x8*)(arow + k0);
#pragma unroll
    for (int nt = 0; nt < 4; nt++) {
      f16x8 b = *(const f16x8*)(Wt + (size_t)(n0 + nt*16 + lr)*Kp + k0 + lc*8);
      acc[nt] = MFMA_F16(a, b, acc[nt]);
    }
  }
#pragma unroll
  for (int nt = 0; nt < 4; nt++) {
    float bb = bias[n0 + nt*16 + lr];
#pragma unroll
    for (int j = 0; j < 4; j++) {
      float vv = fmaxf(acc[nt][j] + bb, 0.f);
      H[(size_t)(m0 + lc*4 + j)*HH + n0 + nt*16 + lr] = (half_t)vv;
    }
  }
}

// ---------------- stageA (MFMA): u'[rc][bv][c'] = sum_x hv[bv][r*32+x] * T''[r][c'][x] ------
__global__ __launch_bounds__(256) void stageA_mfma_kernel(const half_t* __restrict__ hv,
                                                          const half_t* __restrict__ Tpp,
                                                          half_t* __restrict__ u, int r0)
{
  int rc = blockIdx.z; int r = r0 + rc;
  int w = threadIdx.x >> 6, lane = threadIdx.x & 63;
  int m0 = blockIdx.x*64 + w*16;
  int n0 = blockIdx.y*256;
  int lr = lane & 15, lc = lane >> 4;
  f16x8 a = *(const f16x8*)(hv + (size_t)(m0 + lr)*HH + r*HDm + lc*8);
  const half_t* tb = Tpp + ((size_t)r << 16) + (size_t)n0*32 + lc*8;
  f32x4 acc[16];
#pragma unroll
  for (int nt = 0; nt < 16; nt++) {
    f16x8 b = *(const f16x8*)(tb + nt*16*32 + lr*32);
    acc[nt] = MFMA_F16(a, b, (f32x4)(0.f));
  }
  half_t* ub = u + ((size_t)rc*NBV + m0)*2048 + n0;
#pragma unroll
  for (int nt = 0; nt < 16; nt++) {
#pragma unroll
    for (int j = 0; j < 4; j++) {
      ub[(size_t)(lc*4 + j)*2048 + nt*16 + lr] = (half_t)acc[nt][j];
    }
  }
}

// ---------------- triBC (MFMA, barrier-free): per (b, 4 v): logits += sum_r (qt.u).kt^T -----
// grid (25, 64), 256 thr = 4 independent waves, wave w -> bv = b*100 + vt*4 + w.
// Stage B swapped: wT[zg][q] = mfma(A=u-frag, B=qt-frag). Packed per-wave LDS transpose
// ([t][g][mt][q][lg], 2048 dwords/wave) turns wT into stage-C A-frags:
//   am dword s at lane l = pack(regs g, g+2) of tile t=l>>4 from source lane (l&15)+16s.
// Writes: 32x ds_write_b32, 2-way (free). Reads: 8x ds_read_b128, minimal phases. No barriers.
__global__ __launch_bounds__(256,2) void triBC_mfma_kernel(const half_t* __restrict__ hq,
                                                           const half_t* __restrict__ hk,
                                                           const half_t* __restrict__ u,
                                                           const float* __restrict__ maskv,
                                                           float* __restrict__ logits,
                                                           float* __restrict__ pm,
                                                           float* __restrict__ ps,
                                                           int r0, int RC, int isFirst, int isLast)
{
  __shared__ uint32_t wlds[4][2048];   // 8KB per wave
  int tid = threadIdx.x;
  int w = tid >> 6, lane = tid & 63;
  uint32_t* wme = wlds[w];
  int vt = blockIdx.x, b = blockIdx.y;
  int bv = b*VN + vt*4 + w;
  int lr = lane & 15, lc = lane >> 4;

  f32x4 acc[2][4][4];
#pragma unroll
  for (int g=0;g<2;g++)
#pragma unroll
    for (int mt=0;mt<4;mt++)
#pragma unroll
      for (int nt=0;nt<4;nt++) acc[g][mt][nt] = (f32x4)(0.f);

  // per-lane fragment base pointers (advance by 32 halves per rank)
  const half_t* qbase = hq + (size_t)(b*QN + lr)*HH + lc*8;
  const half_t* kbase = hk + (size_t)(b*KN + lr)*HH + lc*8;
  const half_t* ubase = u + ((size_t)bv)*2048 + lr*32 + lc*8;

  for (int rc = 0; rc < RC; rc++) {
    int r = r0 + rc;
    // fragment loads (all global; qt/kt L2-hot, u streaming)
    f16x8 uA[4], qB[4], kB[4];
#pragma unroll
    for (int t=0;t<4;t++)  uA[t]  = *(const f16x8*)(ubase + (size_t)rc*NBV*2048 + t*16*32);
#pragma unroll
    for (int mt=0;mt<4;mt++) qB[mt] = *(const f16x8*)(qbase + mt*16*HH + r*HDm);
#pragma unroll
    for (int nt=0;nt<4;nt++) kB[nt] = *(const f16x8*)(kbase + nt*16*HH + r*HDm);

    // stage B: wT[zg][q] tiles, packed straight into LDS
#pragma unroll
    for (int t=0;t<4;t++) {
#pragma unroll
      for (int mt=0;mt<4;mt++) {
        f32x4 d = MFMA_F16(uA[t], qB[mt], (f32x4)(0.f));
        union { uint32_t u32; half_t h[2]; } p0, p1;
        p0.h[0] = (half_t)d[0]; p0.h[1] = (half_t)d[2];   // g=0: regs (0,2)
        p1.h[0] = (half_t)d[1]; p1.h[1] = (half_t)d[3];   // g=1: regs (1,3)
        wme[(t*8 + 0*4 + mt)*64 + lr*4 + lc] = p0.u32;
        wme[(t*8 + 1*4 + mt)*64 + lr*4 + lc] = p1.u32;
      }
    }

    // stage C: am = b128 reads of own tile (t = lane>>4), k-frags direct
#pragma unroll
    for (int g=0;g<2;g++) {
      f16x8 am[4];
#pragma unroll
      for (int mt=0;mt<4;mt++)
        am[mt] = *(const f16x8*)&wme[(lc*8 + g*4 + mt)*64 + lr*4];
#pragma unroll
      for (int mt=0;mt<4;mt++)
#pragma unroll
        for (int nt=0;nt<4;nt++)
          acc[g][mt][nt] = MFMA_F16(am[mt], kB[nt], acc[g][mt][nt]);
    }
  }

  // epilogue (unchanged): D_C[q][k] -> logits[bv][q][k][g], mask, online softmax partials
  float mk = maskv[bv];
  float* lbase = logits + (size_t)bv*QN*KN*GG;
#pragma unroll
  for (int mt=0;mt<4;mt++)
#pragma unroll
    for (int nt=0;nt<4;nt++)
#pragma unroll
      for (int j=0;j<4;j++) {
        size_t off = ((size_t)(mt*16 + lc*4 + j)*KN + nt*16 + lr)*GG;
        float g0 = acc[0][mt][nt][j], g1 = acc[1][mt][nt][j];
        if (!isFirst) { float2 prev = *(const float2*)(lbase + off); g0 += prev.x; g1 += prev.y; }
        if (isLast && mk != 0.f) { g0 = MASK_VAL; g1 = MASK_VAL; }
        *(float2*)(lbase + off) = make_float2(g0, g1);
        acc[0][mt][nt][j] = g0; acc[1][mt][nt][j] = g1;
      }
  if (isLast) {
#pragma unroll
    for (int g=0; g<2; g++) {
      float mloc = acc[g][0][0][0];
#pragma unroll
      for (int mt=0;mt<4;mt++)
#pragma unroll
        for (int nt=0;nt<4;nt++)
#pragma unroll
          for (int j=0;j<4;j++) mloc = fmaxf(mloc, acc[g][mt][nt][j]);
      float sloc = 0.f;
#pragma unroll
      for (int mt=0;mt<4;mt++)
#pragma unroll
        for (int nt=0;nt<4;nt++)
#pragma unroll
          for (int j=0;j<4;j++) sloc += __expf(acc[g][mt][nt][j] - mloc);
#pragma unroll
      for (int off2=1; off2<64; off2<<=1) {
        float m2 = __shfl_xor(mloc, off2);
        float s2 = __shfl_xor(sloc, off2);
        float mn = fmaxf(mloc, m2);
        sloc = sloc*__expf(mloc-mn) + s2*__expf(m2-mn);
        mloc = mn;
      }
      if (lane == 0) { pm[(size_t)bv*GG + g] = mloc; ps[(size_t)bv*GG + g] = sloc; }
    }
  }
}

// ---------------- combine per-(b,g) partials over 100 v ----------------
__global__ __launch_bounds__(64) void combine_kernel(const float* __restrict__ pm,
                                                     const float* __restrict__ ps,
                                                     float* __restrict__ Mg, float* __restrict__ Sg)
{
  int bg = blockIdx.x; int b = bg >> 1, g = bg & 1;
  int lane = threadIdx.x;
  float m = pm[((size_t)b*VN + lane)*GG + g];
  float s = ps[((size_t)b*VN + lane)*GG + g];
  if (lane + 64 < VN) {
    float m2 = pm[((size_t)b*VN + lane + 64)*GG + g];
    float s2 = ps[((size_t)b*VN + lane + 64)*GG + g];
    float mn = fmaxf(m, m2);
    s = s*__expf(m-mn) + s2*__expf(m2-mn); m = mn;
  }
#pragma unroll
  for (int off=1; off<64; off<<=1) {
    float m2 = __shfl_xor(m, off);
    float s2 = __shfl_xor(s, off);
    float mn = fmaxf(m, m2);
    s = s*__expf(m-mn) + s2*__expf(m2-mn);
    m = mn;
  }
  if (lane == 0) { Mg[b*GG+g] = m; Sg[b*GG+g] = s; }
}

// ---------------- p = exp(logits - M)/S ----------------
__global__ __launch_bounds__(256) void pwrite_kernel(const float* __restrict__ logits,
                                                     const float* __restrict__ Mg,
                                                     const float* __restrict__ Sg,
                                                     float* __restrict__ p)
{
  size_t stride = (size_t)gridDim.x * 256;
  const size_t n4 = LOGN/4;
  for (size_t idx = (size_t)blockIdx.x*256 + threadIdx.x; idx < n4; idx += stride){
    size_t e = idx*4;
    int b = (int)(e / ((size_t)VN*QN*KN*GG));
    float M0 = Mg[b*2], M1 = Mg[b*2+1];
    float iS0 = 1.f/Sg[b*2], iS1 = 1.f/Sg[b*2+1];
    float4 x = *(const float4*)&logits[e];
    float4 o;
    o.x = __expf(x.x - M0)*iS0;
    o.y = __expf(x.y - M1)*iS1;
    o.z = __expf(x.z - M0)*iS0;
    o.w = __expf(x.w - M1)*iS1;
    *(float4*)&p[e] = o;
  }
}

extern "C" void kernel_launch(void* const* d_in, const int* in_sizes, int n_in,
                              void* d_out, int out_size, void* d_ws, size_t ws_size,
                              hipStream_t stream)
{
  const float* v   = (const float*)d_in[0];
  const float* q   = (const float*)d_in[1];
  const float* kg  = (const float*)d_in[2];
  const float* Wv  = (const float*)d_in[3];
  const float* bv  = (const float*)d_in[4];
  const float* Wq  = (const float*)d_in[5];
  const float* bq  = (const float*)d_in[6];
  const float* Wkg = (const float*)d_in[7];
  const float* bkg = (const float*)d_in[8];
  const float* Tg  = (const float*)d_in[9];
  float* p_out  = (float*)d_out;
  float* logits = p_out + LOGN;

  char* ws = (char*)d_ws;
  size_t off = 0;
  auto alloc = [&](size_t bytes) -> char* {
    char* ptr = ws + off;
    off = (off + bytes + 255) & ~(size_t)255;
    return ptr;
  };
  half_t* h_v16 = (half_t*)alloc((size_t)NBV*HH*2);
  half_t* h_q16 = (half_t*)alloc((size_t)Bb*QN*HH*2);
  half_t* h_k16 = (half_t*)alloc((size_t)Bb*KN*HH*2);
  half_t* v16   = (half_t*)alloc((size_t)NBV*VD*2);
  half_t* q16   = (half_t*)alloc((size_t)Bb*QN*QD*2);
  half_t* k16   = (half_t*)alloc((size_t)Bb*KN*KGP*2);
  half_t* Wvt   = (half_t*)alloc((size_t)HH*VD*2);
  half_t* Wqt   = (half_t*)alloc((size_t)HH*QD*2);
  half_t* Wkt   = (half_t*)alloc((size_t)HH*KGP*2);
  half_t* Tpp   = (half_t*)alloc((size_t)32*65536*2);
  float* maskv  = (float*)alloc((size_t)NBV*4);
  float* pm     = (float*)alloc((size_t)NBV*GG*4);
  float* ps     = (float*)alloc((size_t)NBV*GG*4);
  float* Mg     = (float*)alloc(128*4);
  float* Sg     = (float*)alloc(128*4);
  size_t WS_FIXED = off;
  const size_t USZB = (size_t)NBV*2048*2;   // 26,214,400 bytes per r-slice

  int RC; half_t* u;
  if      (WS_FIXED + 32*USZB <= ws_size) { RC = 32; u = (half_t*)(ws + off); }
  else if (WS_FIXED + 16*USZB <= ws_size) { RC = 16; u = (half_t*)(ws + off); }
  else if (WS_FIXED +  8*USZB <= ws_size) { RC =  8; u = (half_t*)(ws + off); }
  else { RC = 8; u = (half_t*)p_out; }      // p region = exactly 8 slices; rewritten at end

  auto nb = [](size_t total) { return (unsigned)((total + 255) / 256); };

  // casts / permute / mask
  cast2d_kernel<<<nb((size_t)NBV*VD),256,0,stream>>>(v,  v16, NBV,   VD,  NBV,   VD);
  cast2d_kernel<<<nb((size_t)Bb*QN*QD),256,0,stream>>>(q,  q16, Bb*QN, QD,  Bb*QN, QD);
  cast2d_kernel<<<nb((size_t)Bb*KN*KGP),256,0,stream>>>(kg, k16, Bb*KN, KGP, Bb*KN, KGD);
  castT_kernel<<<nb((size_t)HH*VD),256,0,stream>>>(Wv,  Wvt, VD,  VD);
  castT_kernel<<<nb((size_t)HH*QD),256,0,stream>>>(Wq,  Wqt, QD,  QD);
  castT_kernel<<<nb((size_t)HH*KGP),256,0,stream>>>(Wkg, Wkt, KGP, KGD);
  permT_kernel<<<nb((size_t)32*65536),256,0,stream>>>(Tg, Tpp);
  mask_kernel<<<NBV,256,0,stream>>>(v, maskv);

  // projections (MFMA)
  proj_mfma_kernel<<<dim3(NBV/64,16),256,0,stream>>>(v16, Wvt, bv,  h_v16, VD);
  proj_mfma_kernel<<<dim3(Bb*QN/64,16),256,0,stream>>>(q16, Wqt, bq,  h_q16, QD);
  proj_mfma_kernel<<<dim3(Bb*KN/64,16),256,0,stream>>>(k16, Wkt, bkg, h_k16, KGP);

  for (int r0 = 0; r0 < RR; r0 += RC) {
    stageA_mfma_kernel<<<dim3(100,8,RC),256,0,stream>>>(h_v16, Tpp, u, r0);
    triBC_mfma_kernel<<<dim3(25,Bb),256,0,stream>>>(h_q16, h_k16, u, maskv, logits, pm, ps,
                                                    r0, RC, (r0==0)?1:0, (r0+RC>=RR)?1:0);
  }
  combine_kernel<<<128,64,0,stream>>>(pm, ps, Mg, Sg);
  pwrite_kernel<<<2048,256,0,stream>>>(logits, Mg, Sg, p_out);
}